// Round 16
// baseline (546.896 us; speedup 1.0000x reference)
//
#include <hip/hip_runtime.h>

#define NN 50000

typedef __attribute__((ext_vector_type(8))) short s16x8;
typedef __attribute__((ext_vector_type(8))) unsigned short u16x8;
typedef __attribute__((ext_vector_type(4))) float f32x4;

__device__ inline unsigned short f2bf(float f) {
    unsigned u = __float_as_uint(f);
    u += 0x7fff + ((u >> 16) & 1);  // RNE
    return (unsigned short)(u >> 16);
}
__device__ inline float bf2f(unsigned short h) { return __uint_as_float((unsigned)h << 16); }
__device__ inline float blo(unsigned u) { return __uint_as_float(u << 16); }
__device__ inline float bhi(unsigned u) { return __uint_as_float(u & 0xffff0000u); }

// ---------------- degree (int); nt load keeps deg lines resident in L2 ----------------
__global__ __launch_bounds__(256) void k_deg(const int* __restrict__ dst, int E,
                                             int* __restrict__ deg) {
    int e = blockIdx.x * 256 + threadIdx.x;
    if (e < E) {
        int d = __builtin_nontemporal_load(&dst[e]);
        atomicAdd(&deg[d], 1);
    }
}

// ---------------- block sums of deg (+ fused dinv) ----------------
__global__ __launch_bounds__(1024) void k_bsum_dinv(const int* __restrict__ deg,
                                                    float* __restrict__ dinv,
                                                    int* __restrict__ bsum, int n) {
    const int tid = threadIdx.x;
    const int i = blockIdx.x * 1024 + tid;
    int v = 0;
    if (i < n) {
        v = deg[i];
        dinv[i] = rsqrtf((float)v + 1.0f);  // +1 self-loop
    }
    int s = v;
#pragma unroll
    for (int off = 32; off; off >>= 1) s += __shfl_down(s, off, 64);
    __shared__ int ws[16];
    if ((tid & 63) == 0) ws[tid >> 6] = s;
    __syncthreads();
    if (tid < 16) {
        int t = ws[tid];
#pragma unroll
        for (int off = 8; off; off >>= 1) t += __shfl_down(t, off, 16);
        if (tid == 0) bsum[blockIdx.x] = t;
    }
}

// ---------------- scan of <=64 block sums -> block offsets ----------------
__global__ __launch_bounds__(64) void k_pscan(const int* __restrict__ bsum,
                                              int* __restrict__ boff, int nb,
                                              int* __restrict__ rowp_last, int E) {
    const int tid = threadIdx.x;
    int v = (tid < nb) ? bsum[tid] : 0;
    int s = v;
#pragma unroll
    for (int off = 1; off < 64; off <<= 1) {
        int t = __shfl_up(s, off, 64);
        if (tid >= off) s += t;
    }
    if (tid < nb) boff[tid] = s - v;
    if (tid == 0) *rowp_last = E;
}

// ---------------- per-block exclusive scan + offset -> row_ptr & cursor ----------------
__global__ __launch_bounds__(1024) void k_scan2(const int* __restrict__ deg,
                                                const int* __restrict__ boff,
                                                int* __restrict__ rowp,
                                                int* __restrict__ cursor, int n) {
    const int tid = threadIdx.x;
    const int i = blockIdx.x * 1024 + tid;
    const int wid = tid >> 6, lane = tid & 63;
    int v = (i < n) ? deg[i] : 0;
    int s = v;
#pragma unroll
    for (int off = 1; off < 64; off <<= 1) {
        int t = __shfl_up(s, off, 64);
        if (lane >= off) s += t;
    }
    __shared__ int ws[16];
    if (lane == 63) ws[wid] = s;
    __syncthreads();
    if (wid == 0) {
        int t = (lane < 16) ? ws[lane] : 0;
#pragma unroll
        for (int off = 1; off < 16; off <<= 1) {
            int u = __shfl_up(t, off, 64);
            if (lane >= off) t += u;
        }
        if (lane < 16) ws[lane] = t;
    }
    __syncthreads();
    const int woff = wid ? ws[wid - 1] : 0;
    if (i < n) {
        int excl = boff[blockIdx.x] + woff + s - v;
        rowp[i] = excl;
        cursor[i] = excl;
    }
}

// ---------------- bin edges by dst: ushort src index; nt loads spare L2 for e_src ------
__global__ __launch_bounds__(256) void k_bin(const int* __restrict__ src,
                                             const int* __restrict__ dst,
                                             int* __restrict__ cursor,
                                             unsigned short* __restrict__ e_src, int E) {
    int e = blockIdx.x * 256 + threadIdx.x;
    if (e >= E) return;
    int s = __builtin_nontemporal_load(&src[e]);
    int d = __builtin_nontemporal_load(&dst[e]);
    int slot = atomicAdd(&cursor[d], 1);
    e_src[slot] = (unsigned short)s;
}

// ---------------- f32 -> bf16 convert (vectorized) ----------------
__global__ __launch_bounds__(256) void k_cvt_bf(const float* __restrict__ in,
                                                unsigned short* __restrict__ out, int n4) {
    int i = blockIdx.x * 256 + threadIdx.x;
    if (i >= n4) return;
    float4 v = ((const float4*)in)[i];
    ((ushort4*)out)[i] = make_ushort4(f2bf(v.x), f2bf(v.y), f2bf(v.z), f2bf(v.w));
}

// ---------------- weight convert: W[K][N] f32 -> Wh/Wl [N][K] bf16, k-permuted ----------
__global__ __launch_bounds__(256) void k_wcvt(const float* __restrict__ W,
                                              unsigned short* __restrict__ Wh,
                                              unsigned short* __restrict__ Wl,
                                              int K, int N) {
    int idx = blockIdx.x * 256 + threadIdx.x;
    if (idx >= K * N) return;
    int k = idx / N, n = idx % N;
    float v = W[idx];
    unsigned short h = f2bf(v);
    unsigned short l = f2bf(v - bf2f(h));
    int klo = k & 31;
    int pos = (k & ~31) + ((klo & 15) >> 2) * 8 + ((klo >> 4) & 1) * 4 + (klo & 3);
    Wh[(size_t)n * K + pos] = h;
    Wl[(size_t)n * K + pos] = l;
}

// ---------------- split-bf16 MFMA GEMM: C[M,N] = A[M,K] * W[K,N] --------
// EPI: +bias+relu. OUTBF: bf16 output. ABF: A is exact bf16 (no lo part, 2 MFMA passes).
template <bool EPI, bool OUTBF, bool ABF>
__global__ __launch_bounds__(256) void mgemm(const void* __restrict__ Av,
                                             const unsigned short* __restrict__ Wh,
                                             const unsigned short* __restrict__ Wl,
                                             const float* __restrict__ bias,
                                             void* __restrict__ Cv,
                                             int M, int N, int K) {
    __shared__ unsigned short Ah[64 * 64];
    __shared__ unsigned short Al[(ABF ? 1 : 64) * 64];
    __shared__ unsigned short Bh[64 * 64], Bl[64 * 64];
    const int tid = threadIdx.x;
    const int bm = blockIdx.y * 64;
    const int bn = blockIdx.x * 64;
    const int wid = tid >> 6, lane = tid & 63;
    const int wr = (wid >> 1) * 32, wc = (wid & 1) * 32;
    const int l15 = lane & 15, lg = lane >> 4;

    const float* Af = (const float*)Av;
    const unsigned short* Ab = (const unsigned short*)Av;

    f32x4 acc[2][2] = {};

    // f32-A staging map
    const int srow = tid >> 4;
    const int sk0 = (tid & 15) * 4;
    const int sb = (sk0 >> 5) * 64 + (((sk0 & 15) >> 2) * 8 + ((sk0 >> 4) & 1) * 4) * 2;
    // bf16-A staging map
    const int srow2 = tid >> 3;
    const int sk0b = (tid & 7) * 8;
    const int sb0 = (sk0b >> 5) * 64 + (((sk0b & 15) >> 2) * 8 + ((sk0b >> 4) & 1) * 4) * 2;
    const int sk1b = sk0b + 4;
    const int sb1 = (sk1b >> 5) * 64 + (((sk1b & 15) >> 2) * 8 + ((sk1b >> 4) & 1) * 4) * 2;
    // B staging map
    const int bcol = tid >> 2;
    const int bck = (tid & 3) * 32;

    for (int kt = 0; kt < K; kt += 64) {
        if constexpr (!ABF) {
#pragma unroll
            for (int p = 0; p < 4; ++p) {
                const int row = p * 16 + srow;
                const int gr = bm + row;
                float4 v = make_float4(0.f, 0.f, 0.f, 0.f);
                if (gr < M) v = *(const float4*)&Af[(size_t)gr * K + kt + sk0];
                const unsigned short h0 = f2bf(v.x), h1 = f2bf(v.y), h2 = f2bf(v.z),
                                     h3 = f2bf(v.w);
                const unsigned short l0 = f2bf(v.x - bf2f(h0)), l1 = f2bf(v.y - bf2f(h1));
                const unsigned short l2 = f2bf(v.z - bf2f(h2)), l3 = f2bf(v.w - bf2f(h3));
                const int byte = sb ^ ((row & 7) << 4);
                *(ushort4*)((char*)Ah + row * 128 + byte) = make_ushort4(h0, h1, h2, h3);
                *(ushort4*)((char*)Al + row * 128 + byte) = make_ushort4(l0, l1, l2, l3);
            }
        } else {
#pragma unroll
            for (int p = 0; p < 2; ++p) {
                const int row = p * 32 + srow2;
                const int gr = bm + row;
                u16x8 v = {0, 0, 0, 0, 0, 0, 0, 0};
                if (gr < M) v = *(const u16x8*)&Ab[(size_t)gr * K + kt + sk0b];
                const int sw = (row & 7) << 4;
                *(ushort4*)((char*)Ah + row * 128 + (sb0 ^ sw)) =
                    make_ushort4(v[0], v[1], v[2], v[3]);
                *(ushort4*)((char*)Ah + row * 128 + (sb1 ^ sw)) =
                    make_ushort4(v[4], v[5], v[6], v[7]);
            }
        }
        {
            const unsigned short* gh = &Wh[(size_t)(bn + bcol) * K + kt + (bck >> 1)];
            const unsigned short* gl = &Wl[(size_t)(bn + bcol) * K + kt + (bck >> 1)];
            const int byt0 = bck ^ ((bcol & 7) << 4);
            const int byt1 = (bck + 16) ^ ((bcol & 7) << 4);
            *(u16x8*)((char*)Bh + bcol * 128 + byt0) = *(const u16x8*)gh;
            *(u16x8*)((char*)Bh + bcol * 128 + byt1) = *(const u16x8*)(gh + 8);
            *(u16x8*)((char*)Bl + bcol * 128 + byt0) = *(const u16x8*)gl;
            *(u16x8*)((char*)Bl + bcol * 128 + byt1) = *(const u16x8*)(gl + 8);
        }
        __syncthreads();
#pragma unroll
        for (int kk = 0; kk < 2; ++kk) {
            s16x8 ah[2], al[2], bh[2], bl[2];
#pragma unroll
            for (int rf = 0; rf < 2; ++rf) {
                const int row = wr + rf * 16 + l15;
                const int byte = (kk * 64 + lg * 16) ^ ((row & 7) << 4);
                ah[rf] = *(const s16x8*)((const char*)Ah + row * 128 + byte);
                if constexpr (!ABF)
                    al[rf] = *(const s16x8*)((const char*)Al + row * 128 + byte);
            }
#pragma unroll
            for (int cf = 0; cf < 2; ++cf) {
                const int col = wc + cf * 16 + l15;
                const int byte = (kk * 64 + lg * 16) ^ ((col & 7) << 4);
                bh[cf] = *(const s16x8*)((const char*)Bh + col * 128 + byte);
                bl[cf] = *(const s16x8*)((const char*)Bl + col * 128 + byte);
            }
#pragma unroll
            for (int rf = 0; rf < 2; ++rf)
#pragma unroll
                for (int cf = 0; cf < 2; ++cf) {
                    acc[rf][cf] = __builtin_amdgcn_mfma_f32_16x16x32_bf16(ah[rf], bh[cf],
                                                                          acc[rf][cf], 0, 0, 0);
                    acc[rf][cf] = __builtin_amdgcn_mfma_f32_16x16x32_bf16(ah[rf], bl[cf],
                                                                          acc[rf][cf], 0, 0, 0);
                    if constexpr (!ABF)
                        acc[rf][cf] = __builtin_amdgcn_mfma_f32_16x16x32_bf16(
                            al[rf], bh[cf], acc[rf][cf], 0, 0, 0);
                }
        }
        __syncthreads();
    }
    // ---- epilogue: C/D layout col=lane&15, row=(lane>>4)*4+reg (m89-verified)
#pragma unroll
    for (int rf = 0; rf < 2; ++rf)
#pragma unroll
        for (int cf = 0; cf < 2; ++cf) {
            const int col = bn + wc + cf * 16 + l15;
            const float bv = EPI ? bias[col] : 0.f;
#pragma unroll
            for (int r = 0; r < 4; ++r) {
                const int gr = bm + wr + rf * 16 + lg * 4 + r;
                if (gr < M) {
                    float v = acc[rf][cf][r];
                    if (EPI) v = fmaxf(v + bv, 0.f);
                    if constexpr (OUTBF)
                        ((unsigned short*)Cv)[(size_t)gr * N + col] = f2bf(v);
                    else
                        ((float*)Cv)[(size_t)gr * N + col] = v;
                }
            }
        }
}

// ---------------- CSR aggregate over bf16 rows (paired half-waves) ----------------
template <bool BIAS_RELU>
__global__ __launch_bounds__(256) void k_agg(const int* __restrict__ row_ptr,
                                             const unsigned short* __restrict__ e_src,
                                             const unsigned short* __restrict__ hb,
                                             const float* __restrict__ dinv,
                                             const float* __restrict__ bias,
                                             float* __restrict__ out, int n) {
    const int node = (blockIdx.x * 256 + threadIdx.x) >> 6;
    const int lane = threadIdx.x & 63;
    const int half = lane >> 5, l32 = lane & 31;
    if (node >= n) return;
    const int beg = row_ptr[node], end = row_ptr[node + 1];
    const float dn = dinv[node];

    float a0 = 0.f, a1 = 0.f, a2 = 0.f, a3 = 0.f;
    int e = beg;
    for (; e + 7 < end; e += 8) {
        const int s0 = e_src[e + half], s1 = e_src[e + 2 + half];
        const int s2 = e_src[e + 4 + half], s3 = e_src[e + 6 + half];
        const float n0 = dinv[s0] * dn, n1 = dinv[s1] * dn;
        const float n2 = dinv[s2] * dn, n3 = dinv[s3] * dn;
        const uint2 v0 = *(const uint2*)&hb[(size_t)s0 * 128 + l32 * 4];
        const uint2 v1 = *(const uint2*)&hb[(size_t)s1 * 128 + l32 * 4];
        const uint2 v2 = *(const uint2*)&hb[(size_t)s2 * 128 + l32 * 4];
        const uint2 v3 = *(const uint2*)&hb[(size_t)s3 * 128 + l32 * 4];
        a0 += blo(v0.x) * n0 + blo(v1.x) * n1 + blo(v2.x) * n2 + blo(v3.x) * n3;
        a1 += bhi(v0.x) * n0 + bhi(v1.x) * n1 + bhi(v2.x) * n2 + bhi(v3.x) * n3;
        a2 += blo(v0.y) * n0 + blo(v1.y) * n1 + blo(v2.y) * n2 + blo(v3.y) * n3;
        a3 += bhi(v0.y) * n0 + bhi(v1.y) * n1 + bhi(v2.y) * n2 + bhi(v3.y) * n3;
    }
    for (; e + 1 < end; e += 2) {
        const int s = e_src[e + half];
        const float nr = dinv[s] * dn;
        const uint2 v = *(const uint2*)&hb[(size_t)s * 128 + l32 * 4];
        a0 += blo(v.x) * nr;
        a1 += bhi(v.x) * nr;
        a2 += blo(v.y) * nr;
        a3 += bhi(v.y) * nr;
    }
    if (e < end && half == 0) {
        const int s = e_src[e];
        const float nr = dinv[s] * dn;
        const uint2 v = *(const uint2*)&hb[(size_t)s * 128 + l32 * 4];
        a0 += blo(v.x) * nr;
        a1 += bhi(v.x) * nr;
        a2 += blo(v.y) * nr;
        a3 += bhi(v.y) * nr;
    }
    // combine the two half-wave partials (same cols, disjoint edges)
    a0 += __shfl_xor(a0, 32, 64);
    a1 += __shfl_xor(a1, 32, 64);
    a2 += __shfl_xor(a2, 32, 64);
    a3 += __shfl_xor(a3, 32, 64);

    if (half == 0) {
        const uint2 vs = *(const uint2*)&hb[(size_t)node * 128 + l32 * 4];
        const float d2 = dn * dn;
        a0 += blo(vs.x) * d2;
        a1 += bhi(vs.x) * d2;
        a2 += blo(vs.y) * d2;
        a3 += bhi(vs.y) * d2;
        if constexpr (BIAS_RELU) {
            const float4 bv = *(const float4*)&bias[l32 * 4];
            a0 = fmaxf(a0 + bv.x, 0.f);
            a1 = fmaxf(a1 + bv.y, 0.f);
            a2 = fmaxf(a2 + bv.z, 0.f);
            a3 = fmaxf(a3 + bv.w, 0.f);
        }
        *(float4*)&out[(size_t)node * 128 + l32 * 4] = make_float4(a0, a1, a2, a3);
    }
}

extern "C" void kernel_launch(void* const* d_in, const int* in_sizes, int n_in,
                              void* d_out, int out_size, void* d_ws, size_t ws_size,
                              hipStream_t stream) {
    const float* x[2] = {(const float*)d_in[0], (const float*)d_in[2]};
    const int* eidx[2] = {(const int*)d_in[1], (const int*)d_in[3]};
    const int E[2] = {in_sizes[1] / 2, in_sizes[3] / 2};
    const float* W1 = (const float*)d_in[4];
    const float* b1 = (const float*)d_in[5];
    const float* W2 = (const float*)d_in[6];
    const float* b2 = (const float*)d_in[7];
    float* out = (float*)d_out;

    const int Emax = (E[0] > E[1]) ? E[0] : E[1];
    char* ws = (char*)d_ws;
    size_t off = 0;
    auto alloc = [&](size_t bytes) -> void* {
        void* p = ws + off;
        off = (off + bytes + 255) & ~(size_t)255;
        return p;
    };
    float* aggX = (float*)alloc((size_t)NN * 128 * 4);                    // Âx (f32, GEMM1 A)
    unsigned short* x1_bf = (unsigned short*)alloc((size_t)NN * 256 * 2); // layer-1 act (bf16)
    unsigned short* x_bf = (unsigned short*)alloc((size_t)NN * 128 * 2);  // x in bf16 (gather)
    unsigned short* h2_bf = (unsigned short*)alloc((size_t)NN * 128 * 2); // h2 in bf16 (gather)
    unsigned short* W1h = (unsigned short*)alloc(128 * 256 * 2);
    unsigned short* W1l = (unsigned short*)alloc(128 * 256 * 2);
    unsigned short* W2h = (unsigned short*)alloc(256 * 128 * 2);
    unsigned short* W2l = (unsigned short*)alloc(256 * 128 * 2);
    int* deg = (int*)alloc((size_t)NN * 4);
    float* dinv = (float*)alloc((size_t)NN * 4);
    int* rowp = (int*)alloc((size_t)(NN + 1) * 4);
    int* cursor = (int*)alloc((size_t)NN * 4);
    int* bsum = (int*)alloc(64 * 4);
    int* boff = (int*)alloc(64 * 4);
    unsigned short* e_src = (unsigned short*)alloc((size_t)Emax * 2);

    const int NB = (NN + 1023) / 1024;  // 49

    // weights: convert+transpose+permute once per call
    k_wcvt<<<(128 * 256 + 255) / 256, 256, 0, stream>>>(W1, W1h, W1l, 128, 256);
    k_wcvt<<<(256 * 128 + 255) / 256, 256, 0, stream>>>(W2, W2h, W2l, 256, 128);

    for (int g = 0; g < 2; ++g) {
        const int Eg = E[g];
        const int* srcp = eidx[g];
        const int* dstp = eidx[g] + Eg;

        // ---- CSR build + x convert
        hipMemsetAsync(deg, 0, NN * sizeof(int), stream);
        k_cvt_bf<<<(NN * 128 / 4 + 255) / 256, 256, 0, stream>>>(x[g], x_bf, NN * 128 / 4);
        k_deg<<<(Eg + 255) / 256, 256, 0, stream>>>(dstp, Eg, deg);
        k_bsum_dinv<<<NB, 1024, 0, stream>>>(deg, dinv, bsum, NN);
        k_pscan<<<1, 64, 0, stream>>>(bsum, boff, NB, &rowp[NN], Eg);
        k_scan2<<<NB, 1024, 0, stream>>>(deg, boff, rowp, cursor, NN);
        k_bin<<<(Eg + 255) / 256, 256, 0, stream>>>(srcp, dstp, cursor, e_src, Eg);

        // ---- layer 1 (aggregate-first): aggX = Â x ; x1 = relu(aggX @ W1 + b1) [bf16]
        k_agg<false><<<(NN + 3) / 4, 256, 0, stream>>>(rowp, e_src, x_bf, dinv, nullptr,
                                                       aggX, NN);
        mgemm<true, true, false><<<dim3(256 / 64, (NN + 63) / 64), 256, 0, stream>>>(
            aggX, W1h, W1l, b1, x1_bf, NN, 256, 128);

        // ---- layer 2 (aggregate-last): h2 = x1 @ W2 (bf16 A, 2-pass); out = relu(Â h2 + b2)
        mgemm<false, true, true><<<dim3(128 / 64, (NN + 63) / 64), 256, 0, stream>>>(
            x1_bf, W2h, W2l, nullptr, h2_bf, NN, 128, 256);
        k_agg<true><<<(NN + 3) / 4, 256, 0, stream>>>(rowp, e_src, h2_bf, dinv, b2,
                                                      out + (size_t)g * NN * 128, NN);
    }
}